// Round 2
// baseline (241.066 us; speedup 1.0000x reference)
//
#include <hip/hip_runtime.h>
#include <hip/hip_bf16.h>
#include <stdint.h>
#include <string.h>

typedef __bf16 bf16x8 __attribute__((ext_vector_type(8)));
typedef float  f32x4  __attribute__((ext_vector_type(4)));

// Convert 8 consecutive fp32 (two float4s) to a bf16x8 MFMA fragment (RNE).
static __device__ inline bf16x8 cvt8(const float4 a, const float4 b) {
    bf16x8 r;
    r[0] = (__bf16)a.x; r[1] = (__bf16)a.y; r[2] = (__bf16)a.z; r[3] = (__bf16)a.w;
    r[4] = (__bf16)b.x; r[5] = (__bf16)b.y; r[6] = (__bf16)b.z; r[7] = (__bf16)b.w;
    return r;
}

// One wave processes 16 edges:
//   A tile  = concat(z_user[row], z_books[col])  [16 edges x 128 feats], fp32
//             -> bf16 in registers
//   B tiles = W1^T [128 x 64] -> 4 N-tiles x 4 K-steps of mfma_f32_16x16x32_bf16
//   h = relu(A@W1^T + b1)  (accum + epilogue fp32); out = h.W2 + b2 (fp32 VALU)
// MFMA 16x16x32 bf16 layouts (measured, cdna_hip_programming.md §3):
//   A: lane holds A[m=lane&15][k=quad*8+j]  (quad = lane>>4)
//   B: lane holds B[k=quad*8+j][n=lane&15]
//   C/D: lane reg r holds D[row=quad*4+r][col=lane&15]
__global__ __launch_bounds__(256, 4)
void edge_decoder_mfma(const float* __restrict__ zu,
                       const float* __restrict__ zb,
                       const int*   __restrict__ eidx,
                       const float* __restrict__ w1,
                       const float* __restrict__ b1,
                       const float* __restrict__ w2,
                       const float* __restrict__ b2,
                       float*       __restrict__ out,
                       const int nedges)
{
    const int lane = threadIdx.x & 63;
    const int m    = lane & 15;   // A row (edge-in-tile) for A-frag; n&15 for C cols
    const int quad = lane >> 4;

    const int wavesPerBlock = blockDim.x >> 6;
    const int gwave  = blockIdx.x * wavesPerBlock + (threadIdx.x >> 6);
    const int nwaves = gridDim.x * wavesPerBlock;

    // ---- per-wave constants: W1 B-fragments, fp32 -> bf16 once (64 VGPRs) ----
    // Bf[t][s][j] = bf16( W1[n=t*16+m][k=s*32+quad*8+j] ); W1 row = 128 fp32.
    bf16x8 Bf[4][4];
#pragma unroll
    for (int t = 0; t < 4; ++t) {
        const float4* wrow = (const float4*)(w1 + (size_t)(t * 16 + m) * 128);
#pragma unroll
        for (int s = 0; s < 4; ++s) {
            const int c0 = s * 8 + quad * 2;        // float4-chunk index
            Bf[t][s] = cvt8(wrow[c0], wrow[c0 + 1]);
        }
    }

    float w2v[4], b1v[4];
#pragma unroll
    for (int t = 0; t < 4; ++t) {
        w2v[t] = w2[t * 16 + m];     // W2 column for n = t*16+m (fp32, exact)
        b1v[t] = b1[t * 16 + m];
    }
    const float b2f = b2[0];

    const int* __restrict__ rowp = eidx;
    const int* __restrict__ colp = eidx + nedges;

    const int ngroups = (nedges + 15) >> 4;

    for (int g = gwave; g < ngroups; g += nwaves) {
        const int ebase = g << 4;
        int e = ebase + m;
        if (e >= nedges) e = nedges - 1;          // tail clamp (stores masked below)
        const int r = rowp[e];
        const int c = colp[e];

        // Gather: each table row = 64 fp32 = 16 float4 chunks. Lane (m,quad)
        // loads chunks {2q,2q+1, 8+2q,9+2q} of user row and of book row, then
        // converts to bf16 A-fragments in-register.
        const float4* up = (const float4*)(zu + (size_t)r * 64);
        const float4* vp = (const float4*)(zb + (size_t)c * 64);
        bf16x8 A0 = cvt8(up[quad * 2],     up[quad * 2 + 1]);     // k in [0,32)
        bf16x8 A1 = cvt8(up[8 + quad * 2], up[9 + quad * 2]);     // k in [32,64)
        bf16x8 A2 = cvt8(vp[quad * 2],     vp[quad * 2 + 1]);     // k in [64,96)
        bf16x8 A3 = cvt8(vp[8 + quad * 2], vp[9 + quad * 2]);     // k in [96,128)

        f32x4 acc[4];
#pragma unroll
        for (int t = 0; t < 4; ++t) acc[t] = (f32x4){0.f, 0.f, 0.f, 0.f};

#pragma unroll
        for (int t = 0; t < 4; ++t) {
            acc[t] = __builtin_amdgcn_mfma_f32_16x16x32_bf16(A0, Bf[t][0], acc[t], 0, 0, 0);
            acc[t] = __builtin_amdgcn_mfma_f32_16x16x32_bf16(A1, Bf[t][1], acc[t], 0, 0, 0);
            acc[t] = __builtin_amdgcn_mfma_f32_16x16x32_bf16(A2, Bf[t][2], acc[t], 0, 0, 0);
            acc[t] = __builtin_amdgcn_mfma_f32_16x16x32_bf16(A3, Bf[t][3], acc[t], 0, 0, 0);
        }

        // Epilogue (fp32): h[edge][n] = relu(acc + b1[n]); lane-partial dot with
        // W2[n]; reduce over the 16 n-lanes of each quad. Lane holds edges
        // quad*4 + rr of this 16-edge group.
        float p[4] = {0.f, 0.f, 0.f, 0.f};
#pragma unroll
        for (int t = 0; t < 4; ++t) {
#pragma unroll
            for (int rr = 0; rr < 4; ++rr) {
                float h = acc[t][rr] + b1v[t];
                h = fmaxf(h, 0.f);
                p[rr] = fmaf(h, w2v[t], p[rr]);
            }
        }

#pragma unroll
        for (int off = 8; off >= 1; off >>= 1) {
#pragma unroll
            for (int rr = 0; rr < 4; ++rr)
                p[rr] += __shfl_xor(p[rr], off, 64);
        }

        if (m == 0) {
            const int eo = ebase + quad * 4;     // 4 consecutive edges per quad-leader
            if (eo + 3 < nedges) {
                float4 o;
                o.x = p[0] + b2f; o.y = p[1] + b2f;
                o.z = p[2] + b2f; o.w = p[3] + b2f;
                *(float4*)(out + eo) = o;        // 16B-aligned packed store
            } else {
#pragma unroll
                for (int rr = 0; rr < 4; ++rr)
                    if (eo + rr < nedges) out[eo + rr] = p[rr] + b2f;
            }
        }
    }
}

extern "C" void kernel_launch(void* const* d_in, const int* in_sizes, int n_in,
                              void* d_out, int out_size, void* d_ws, size_t ws_size,
                              hipStream_t stream) {
    const float* zu = (const float*)d_in[0];
    const float* zb = (const float*)d_in[1];
    const int*   ei = (const int*)d_in[2];
    const float* w1 = (const float*)d_in[3];
    const float* b1 = (const float*)d_in[4];
    const float* w2 = (const float*)d_in[5];
    const float* b2 = (const float*)d_in[6];
    float* out = (float*)d_out;

    const int nedges = in_sizes[2] / 2;   // edge_label_index is [2, E]

    // 1024 blocks x 256 threads = 4096 waves = full residency at 4 waves/SIMD.
    dim3 grid(1024), block(256);
    hipLaunchKernelGGL(edge_decoder_mfma, grid, block, 0, stream,
                       zu, zb, ei, w1, b1, w2, b2, out, nedges);
}